// Round 6
// baseline (415.334 us; speedup 1.0000x reference)
//
#include <hip/hip_runtime.h>
#include <math.h>

#define BB 16
#define LL 512
#define DD 768
#define HH 12
#define DHH 64
#define SPDD 5
#define MM (BB*LL)   // 8192
#define LN_EPS 1e-5f
#define CLAMP_MINV 1e-6f

typedef __attribute__((ext_vector_type(8))) short bf8_t;
typedef __attribute__((ext_vector_type(4))) float f4_t;

__device__ __forceinline__ short f2bf(float x) {
    unsigned u = __builtin_bit_cast(unsigned, x);
    unsigned r = (u + 0x7FFFu + ((u >> 16) & 1u)) >> 16;
    return (short)r;
}
__device__ __forceinline__ float bf2f(short s) {
    unsigned u = ((unsigned)(unsigned short)s) << 16;
    return __builtin_bit_cast(float, u);
}

__device__ __forceinline__ void gld16(const short* g, short* l) {
    __builtin_amdgcn_global_load_lds(
        (const __attribute__((address_space(1))) unsigned int*)g,
        (__attribute__((address_space(3))) unsigned int*)l,
        16, 0, 0);
}

// ---------------- block reduce (256 threads, wave64) ------------------------
__device__ __forceinline__ float block_sum(float v, float* red, int tid) {
    #pragma unroll
    for (int off = 32; off; off >>= 1) v += __shfl_down(v, off, 64);
    __syncthreads();
    if ((tid & 63) == 0) red[tid >> 6] = v;
    __syncthreads();
    return red[0] + red[1] + red[2] + red[3];
}

// ---------------- fused prep: input cast + weight transpose -----------------
// blocks [0,3072): aqk = bf16(tgt+qpos), av = bf16(tgt)
// blocks [3072,3648): Wt[n][k] = bf16(W[k][n]) for 4 weights
__global__ __launch_bounds__(256) void prep_kernel(
    const float* __restrict__ tgt, const float* __restrict__ qpos,
    const float* __restrict__ W0, const float* __restrict__ W1,
    const float* __restrict__ W2, const float* __restrict__ W3,
    short* __restrict__ aqk, short* __restrict__ av,
    short* __restrict__ O0, short* __restrict__ O1,
    short* __restrict__ O2, short* __restrict__ O3)
{
    __shared__ float T[64][65];
    const int t = blockIdx.x;
    if (t < 3072) {
        // ---- input cast ----
        const size_t base = ((size_t)t * 256 + threadIdx.x) * 8;
        const float4 t0 = *(const float4*)(tgt + base);
        const float4 t1 = *(const float4*)(tgt + base + 4);
        const float4 p0 = *(const float4*)(qpos + base);
        const float4 p1 = *(const float4*)(qpos + base + 4);
        short v[8], q[8];
        v[0] = f2bf(t0.x); v[1] = f2bf(t0.y); v[2] = f2bf(t0.z); v[3] = f2bf(t0.w);
        v[4] = f2bf(t1.x); v[5] = f2bf(t1.y); v[6] = f2bf(t1.z); v[7] = f2bf(t1.w);
        q[0] = f2bf(t0.x + p0.x); q[1] = f2bf(t0.y + p0.y);
        q[2] = f2bf(t0.z + p0.z); q[3] = f2bf(t0.w + p0.w);
        q[4] = f2bf(t1.x + p1.x); q[5] = f2bf(t1.y + p1.y);
        q[6] = f2bf(t1.z + p1.z); q[7] = f2bf(t1.w + p1.w);
        *(bf8_t*)(av + base)  = *(bf8_t*)v;
        *(bf8_t*)(aqk + base) = *(bf8_t*)q;
    } else {
        // ---- weight transpose + cast ----
        const int wt = t - 3072;                // 0..575
        const int wi = wt / 144;
        const int rem = wt % 144;
        const float* W; short* O;
        switch (wi) {
            case 0: W = W0; O = O0; break;
            case 1: W = W1; O = O1; break;
            case 2: W = W2; O = O2; break;
            default: W = W3; O = O3; break;
        }
        const int n0 = (rem % 12) * 64, k0 = (rem / 12) * 64;
        const int tid = threadIdx.x;
        {
            const int kk = tid >> 4, nv = (tid & 15) * 4;
            #pragma unroll
            for (int i = 0; i < 4; ++i) {
                const int k = kk + i * 16;
                const float4 v = *(const float4*)(W + (size_t)(k0 + k) * DD + n0 + nv);
                T[k][nv + 0] = v.x; T[k][nv + 1] = v.y;
                T[k][nv + 2] = v.z; T[k][nv + 3] = v.w;
            }
        }
        __syncthreads();
        {
            const int n = tid >> 2, kc = (tid & 3) * 16;
            short tmp[16];
            #pragma unroll
            for (int i = 0; i < 16; ++i) tmp[i] = f2bf(T[kc + i][n]);
            short* dst = O + (size_t)(n0 + n) * DD + k0 + kc;
            *(bf8_t*)dst       = *(bf8_t*)tmp;
            *(bf8_t*)(dst + 8) = *(bf8_t*)(tmp + 8);
        }
    }
}

// ---------------- fused Q/K/V bf16 MFMA GEMM (XCD-swizzled) -----------------
__global__ __launch_bounds__(256) void gemm_qkv(
    const short* __restrict__ Aqk, const short* __restrict__ Av,
    const short* __restrict__ Wq, const float* __restrict__ bq, short* __restrict__ oq,
    const short* __restrict__ Wk, const float* __restrict__ bk, short* __restrict__ ok,
    const short* __restrict__ Wv, const float* __restrict__ bv, short* __restrict__ ov)
{
    __shared__ short As[128 * 64];
    __shared__ short Bs[128 * 64];
    const int id = blockIdx.y * 18 + blockIdx.x;
    const int xcd = id & 7, j = id >> 3;          // j: 0..143
    const int by = xcd * 8 + j / 18;
    const int gx = j % 18;
    const int seg = gx / 6;
    const int bx = gx % 6;
    const short* A  = (seg == 2) ? Av : Aqk;
    const short* Wt = (seg == 0) ? Wq : (seg == 1) ? Wk : Wv;
    const float* bias = (seg == 0) ? bq : (seg == 1) ? bk : bv;
    short* out = (seg == 0) ? oq : (seg == 1) ? ok : ov;

    const int n0 = bx * 128, m0 = by * 128;
    const int tid = threadIdx.x;
    const int w = tid >> 6, lane = tid & 63;
    const int quad = lane >> 4, l16 = lane & 15;
    const int wm = w & 1, wn = w >> 1;
    const int sr = w * 8 + (lane >> 3);
    const int sp = lane & 7;

    f4_t acc[4][4];
    #pragma unroll
    for (int i = 0; i < 4; ++i)
        #pragma unroll
        for (int jj = 0; jj < 4; ++jj) acc[i][jj] = (f4_t){0.f, 0.f, 0.f, 0.f};

    for (int k0 = 0; k0 < DD; k0 += 64) {
        __syncthreads();
        #pragma unroll
        for (int ra = 0; ra < 4; ++ra) {
            const int r = sr + ra * 32;
            const int c = sp ^ (r & 7);
            const int ldso = ra * 2048 + w * 512 + lane * 8;
            gld16(A  + (size_t)(m0 + r) * DD + k0 + c * 8, As + ldso);
            gld16(Wt + (size_t)(n0 + r) * DD + k0 + c * 8, Bs + ldso);
        }
        __syncthreads();
        #pragma unroll
        for (int s = 0; s < 2; ++s) {
            bf8_t a[4], b[4];
            #pragma unroll
            for (int i = 0; i < 4; ++i) {
                const int rA = wm * 64 + i * 16 + l16;
                const int pA = (s * 4 + quad) ^ (rA & 7);
                a[i] = *(const bf8_t*)(As + rA * 64 + pA * 8);
                const int rB = wn * 64 + i * 16 + l16;
                const int pB = (s * 4 + quad) ^ (rB & 7);
                b[i] = *(const bf8_t*)(Bs + rB * 64 + pB * 8);
            }
            #pragma unroll
            for (int i = 0; i < 4; ++i)
                #pragma unroll
                for (int jj = 0; jj < 4; ++jj)
                    acc[i][jj] = __builtin_amdgcn_mfma_f32_16x16x32_bf16(a[i], b[jj], acc[i][jj], 0, 0, 0);
        }
    }

    float bvv[4];
    #pragma unroll
    for (int jj = 0; jj < 4; ++jj) bvv[jj] = bias[n0 + wn * 64 + jj * 16 + l16];
    #pragma unroll
    for (int i = 0; i < 4; ++i) {
        #pragma unroll
        for (int jj = 0; jj < 4; ++jj) {
            const int n = n0 + wn * 64 + jj * 16 + l16;
            #pragma unroll
            for (int r = 0; r < 4; ++r) {
                const int m = m0 + wm * 64 + i * 16 + quad * 4 + r;
                const float val = acc[i][jj][r] + bvv[jj];
                const int b_ = m >> 9, l = m & 511;
                const int h = n >> 6, d = n & 63;
                if (seg < 2)
                    out[(((size_t)(b_ * HH + h)) * LL + l) * DHH + d] = f2bf(val);
                else
                    out[(((size_t)(b_ * HH + h)) * DHH + d) * LL + l] = f2bf(val);
            }
        }
    }
}

// ---------------- O-projection GEMM (XCD-swizzled, fp32 out) ----------------
__global__ __launch_bounds__(256) void gemm_o(
    const short* __restrict__ A, const short* __restrict__ Wt,
    const float* __restrict__ bias, float* __restrict__ out)
{
    __shared__ short As[128 * 64];
    __shared__ short Bs[128 * 64];
    const int id = blockIdx.y * 6 + blockIdx.x;
    const int xcd = id & 7, j = id >> 3;          // j: 0..47
    const int by = xcd * 8 + j / 6;
    const int bx = j % 6;
    const int n0 = bx * 128, m0 = by * 128;
    const int tid = threadIdx.x;
    const int w = tid >> 6, lane = tid & 63;
    const int quad = lane >> 4, l16 = lane & 15;
    const int wm = w & 1, wn = w >> 1;
    const int sr = w * 8 + (lane >> 3);
    const int sp = lane & 7;

    f4_t acc[4][4];
    #pragma unroll
    for (int i = 0; i < 4; ++i)
        #pragma unroll
        for (int jj = 0; jj < 4; ++jj) acc[i][jj] = (f4_t){0.f, 0.f, 0.f, 0.f};

    for (int k0 = 0; k0 < DD; k0 += 64) {
        __syncthreads();
        #pragma unroll
        for (int ra = 0; ra < 4; ++ra) {
            const int r = sr + ra * 32;
            const int c = sp ^ (r & 7);
            const int ldso = ra * 2048 + w * 512 + lane * 8;
            gld16(A  + (size_t)(m0 + r) * DD + k0 + c * 8, As + ldso);
            gld16(Wt + (size_t)(n0 + r) * DD + k0 + c * 8, Bs + ldso);
        }
        __syncthreads();
        #pragma unroll
        for (int s = 0; s < 2; ++s) {
            bf8_t a[4], b[4];
            #pragma unroll
            for (int i = 0; i < 4; ++i) {
                const int rA = wm * 64 + i * 16 + l16;
                const int pA = (s * 4 + quad) ^ (rA & 7);
                a[i] = *(const bf8_t*)(As + rA * 64 + pA * 8);
                const int rB = wn * 64 + i * 16 + l16;
                const int pB = (s * 4 + quad) ^ (rB & 7);
                b[i] = *(const bf8_t*)(Bs + rB * 64 + pB * 8);
            }
            #pragma unroll
            for (int i = 0; i < 4; ++i)
                #pragma unroll
                for (int jj = 0; jj < 4; ++jj)
                    acc[i][jj] = __builtin_amdgcn_mfma_f32_16x16x32_bf16(a[i], b[jj], acc[i][jj], 0, 0, 0);
        }
    }

    float bvv[4];
    #pragma unroll
    for (int jj = 0; jj < 4; ++jj) bvv[jj] = bias[n0 + wn * 64 + jj * 16 + l16];
    #pragma unroll
    for (int i = 0; i < 4; ++i)
        #pragma unroll
        for (int jj = 0; jj < 4; ++jj) {
            const int n = n0 + wn * 64 + jj * 16 + l16;
            #pragma unroll
            for (int r = 0; r < 4; ++r) {
                const int m = m0 + wm * 64 + i * 16 + quad * 4 + r;
                out[(size_t)m * DD + n] = acc[i][jj][r] + bvv[jj];
            }
        }
}

// ---------------- flash-style MFMA attention, inline spatial bias -----------
// grid (12,128) flat-decoded: xcd = id&7 owns 16 (b,qt) pairs × 12 h, so the
// 12 head-blocks sharing one ploc q-stripe (and that b's K/V) sit on one XCD.
// p = la * exp(s - m): softmax(log la + s) without the log.
__global__ __launch_bounds__(256) void attn_mfma(
    const short* __restrict__ Q, const short* __restrict__ K,
    const short* __restrict__ Vt, const float* __restrict__ ploc,
    const float* __restrict__ Wloc, const float* __restrict__ bloc,
    short* __restrict__ out)
{
    __shared__ short Ks[64 * 64];
    __shared__ short Vs[64 * 64];
    __shared__ short bs16[64 * 68];
    __shared__ short Ps[4][16 * 64];

    const int id = blockIdx.y * 12 + blockIdx.x;  // 0..1535
    const int xcd = id & 7, j = id >> 3;          // j: 0..191
    const int pair = xcd * 16 + j / 12;           // 0..127
    const int h = j % 12;
    const int b = pair >> 3, qt = pair & 7;

    const int tid = threadIdx.x;
    const int w = tid >> 6, lane = tid & 63;
    const int quad = lane >> 4, l16 = lane & 15;
    const int q0 = qt * 64;
    const size_t bh = (size_t)b * HH + h;

    float wl[SPDD];
    #pragma unroll
    for (int s = 0; s < SPDD; ++s) wl[s] = Wloc[s * HH + h];
    const float blc = bloc[h];

    const int qr = q0 + w * 16 + l16;
    const bf8_t aq0 = *(const bf8_t*)(Q + (bh * LL + qr) * DHH + quad * 8);
    const bf8_t aq1 = *(const bf8_t*)(Q + (bh * LL + qr) * DHH + quad * 8 + 32);

    f4_t o[4];
    #pragma unroll
    for (int dj = 0; dj < 4; ++dj) o[dj] = (f4_t){0.f, 0.f, 0.f, 0.f};
    float m_row[4], l_row[4];
    #pragma unroll
    for (int r = 0; r < 4; ++r) { m_row[r] = -1e30f; l_row[r] = 0.f; }

    const short* Kg = K  + bh * LL * DHH;
    const short* Vg = Vt + bh * DHH * LL;

    const int srow = tid >> 2;
    const int cb   = (tid & 3) * 2;
    const int sw   = srow & 7;
    const int bl_l = tid >> 2, bl_ts = (tid & 3) * 16;
    const float* plrow = ploc + (((size_t)b * LL + q0 + bl_l) * LL) * SPDD;

    for (int t0 = 0; t0 < LL; t0 += 64) {
        __syncthreads();
        {
            const short* src = Kg + (size_t)(t0 + srow) * DHH + cb * 8;
            *(bf8_t*)(Ks + srow * 64 + ((cb ^ sw) * 8))       = *(const bf8_t*)(src);
            *(bf8_t*)(Ks + srow * 64 + (((cb + 1) ^ sw) * 8)) = *(const bf8_t*)(src + 8);
        }
        {
            const short* src = Vg + (size_t)srow * LL + t0 + cb * 8;
            *(bf8_t*)(Vs + srow * 64 + ((cb ^ sw) * 8))       = *(const bf8_t*)(src);
            *(bf8_t*)(Vs + srow * 64 + (((cb + 1) ^ sw) * 8)) = *(const bf8_t*)(src + 8);
        }
        {
            // inline la tile: 16 t per thread, groups of 4 t (20 floats each)
            const float* pp = plrow + (size_t)(t0 + bl_ts) * SPDD;
            #pragma unroll
            for (int g4 = 0; g4 < 4; ++g4) {
                float p[20];
                #pragma unroll
                for (int c4 = 0; c4 < 5; ++c4)
                    *(float4*)(p + c4 * 4) = *(const float4*)(pp + g4 * 20 + c4 * 4);
                #pragma unroll
                for (int i = 0; i < 4; ++i) {
                    float v = blc;
                    #pragma unroll
                    for (int s = 0; s < SPDD; ++s) v += p[i * SPDD + s] * wl[s];
                    v = fmaxf(fmaxf(v, 0.f), CLAMP_MINV);
                    bs16[bl_l * 68 + bl_ts + g4 * 4 + i] = f2bf(v);
                }
            }
        }
        __syncthreads();

        // ---- S = Q K^T ----
        f4_t sv[4];
        #pragma unroll
        for (int j2 = 0; j2 < 4; ++j2) {
            const int rB = j2 * 16 + l16;
            const int x = rB & 7;
            const bf8_t b0 = *(const bf8_t*)(Ks + rB * 64 + ((quad ^ x) * 8));
            const bf8_t b1 = *(const bf8_t*)(Ks + rB * 64 + (((quad + 4) ^ x) * 8));
            f4_t c = (f4_t){0.f, 0.f, 0.f, 0.f};
            c = __builtin_amdgcn_mfma_f32_16x16x32_bf16(aq0, b0, c, 0, 0, 0);
            c = __builtin_amdgcn_mfma_f32_16x16x32_bf16(aq1, b1, c, 0, 0, 0);
            sv[j2] = c;
        }
        #pragma unroll
        for (int j2 = 0; j2 < 4; ++j2)
            #pragma unroll
            for (int r = 0; r < 4; ++r) sv[j2][r] *= 0.125f;

        // ---- online softmax: p = la * exp(s - m) ----
        #pragma unroll
        for (int r = 0; r < 4; ++r) {
            const int lrel = w * 16 + quad * 4 + r;
            float mx = fmaxf(fmaxf(sv[0][r], sv[1][r]), fmaxf(sv[2][r], sv[3][r]));
            mx = fmaxf(mx, __shfl_xor(mx, 1, 16));
            mx = fmaxf(mx, __shfl_xor(mx, 2, 16));
            mx = fmaxf(mx, __shfl_xor(mx, 4, 16));
            mx = fmaxf(mx, __shfl_xor(mx, 8, 16));
            const float mn = fmaxf(m_row[r], mx);
            const float al = __expf(m_row[r] - mn);
            m_row[r] = mn;
            float rs = 0.f;
            #pragma unroll
            for (int j2 = 0; j2 < 4; ++j2) {
                const float lav = bf2f(bs16[lrel * 68 + j2 * 16 + l16]);
                const float p = lav * __expf(sv[j2][r] - mn);
                sv[j2][r] = p;
                rs += p;
            }
            rs += __shfl_xor(rs, 1, 16);
            rs += __shfl_xor(rs, 2, 16);
            rs += __shfl_xor(rs, 4, 16);
            rs += __shfl_xor(rs, 8, 16);
            l_row[r] = l_row[r] * al + rs;
            #pragma unroll
            for (int dj = 0; dj < 4; ++dj) o[dj][r] *= al;
        }
        // ---- P: C-layout -> swizzled LDS -> A-layout ----
        short* Pw = Ps[w];
        #pragma unroll
        for (int r = 0; r < 4; ++r) {
            const int rp = quad * 4 + r, rp7 = rp & 7;
            #pragma unroll
            for (int j2 = 0; j2 < 4; ++j2) {
                const int t = j2 * 16 + l16;
                Pw[rp * 64 + (((t >> 3) ^ rp7) * 8) + (t & 7)] = f2bf(sv[j2][r]);
            }
        }
        const int m7 = l16 & 7;
        const bf8_t ap0 = *(const bf8_t*)(Pw + l16 * 64 + ((quad ^ m7) * 8));
        const bf8_t ap1 = *(const bf8_t*)(Pw + l16 * 64 + (((quad + 4) ^ m7) * 8));
        #pragma unroll
        for (int dj = 0; dj < 4; ++dj) {
            const int rB = dj * 16 + l16;
            const int x = rB & 7;
            const bf8_t b0 = *(const bf8_t*)(Vs + rB * 64 + ((quad ^ x) * 8));
            const bf8_t b1 = *(const bf8_t*)(Vs + rB * 64 + (((quad + 4) ^ x) * 8));
            o[dj] = __builtin_amdgcn_mfma_f32_16x16x32_bf16(ap0, b0, o[dj], 0, 0, 0);
            o[dj] = __builtin_amdgcn_mfma_f32_16x16x32_bf16(ap1, b1, o[dj], 0, 0, 0);
        }
    }

    #pragma unroll
    for (int r = 0; r < 4; ++r) {
        const int l = q0 + w * 16 + quad * 4 + r;
        const float inv = 1.f / l_row[r];
        short* op = out + ((size_t)b * LL + l) * DD + h * DHH;
        #pragma unroll
        for (int dj = 0; dj < 4; ++dj)
            op[dj * 16 + l16] = f2bf(o[dj][r] * inv);
    }
}

// ---------------- residual + LayerNorm --------------------------------------
__global__ __launch_bounds__(256) void ln_kernel(
    const float* __restrict__ x, const float* __restrict__ tgt,
    const float* __restrict__ g, const float* __restrict__ bta,
    float* __restrict__ out)
{
    const int row = blockIdx.x;
    const int tid = threadIdx.x;
    __shared__ float red[4];

    const float* xp = x + (size_t)row * DD;
    const float* tp = tgt + (size_t)row * DD;

    float vals[3];
    float s = 0.f;
    #pragma unroll
    for (int i = 0; i < 3; ++i) {
        const float v = xp[tid + i * 256] + tp[tid + i * 256];
        vals[i] = v;
        s += v;
    }
    s = block_sum(s, red, tid);
    const float mu = s * (1.f / 768.f);

    float vs = 0.f;
    #pragma unroll
    for (int i = 0; i < 3; ++i) {
        const float dv = vals[i] - mu;
        vs += dv * dv;
    }
    vs = block_sum(vs, red, tid);
    const float rstd = rsqrtf(vs * (1.f / 768.f) + LN_EPS);

    #pragma unroll
    for (int i = 0; i < 3; ++i) {
        const int cidx = tid + i * 256;
        out[(size_t)row * DD + cidx] = g[cidx] * (vals[i] - mu) * rstd + bta[cidx];
    }
}

// ---------------- launch -----------------------------------------------------
extern "C" void kernel_launch(void* const* d_in, const int* in_sizes, int n_in,
                              void* d_out, int out_size, void* d_ws, size_t ws_size,
                              hipStream_t stream) {
    const float* tgt   = (const float*)d_in[0];
    const float* qpos  = (const float*)d_in[1];
    const float* ploc  = (const float*)d_in[2];
    const float* Wq    = (const float*)d_in[3];
    const float* bq    = (const float*)d_in[4];
    const float* Wk    = (const float*)d_in[5];
    const float* bk    = (const float*)d_in[6];
    const float* Wv    = (const float*)d_in[7];
    const float* bv    = (const float*)d_in[8];
    const float* Wo    = (const float*)d_in[9];
    const float* bo    = (const float*)d_in[10];
    const float* Wloc  = (const float*)d_in[11];
    const float* bloc  = (const float*)d_in[12];
    const float* ln_g  = (const float*)d_in[13];
    const float* ln_b  = (const float*)d_in[14];

    const size_t NQ = (size_t)MM * DD;           // 6291456
    const size_t NW = (size_t)DD * DD;           // 589824

    short* qb   = (short*)d_ws;
    short* kb   = qb  + NQ;
    short* vtb  = kb  + NQ;
    short* aob  = vtb + NQ;
    short* aqk  = aob + NQ;
    short* av   = aqk + NQ;
    float* pbuf = (float*)aqk;                   // alias (aqk,av dead by then)
    short* wqt  = av + NQ;
    short* wkt  = wqt + NW;
    short* wvt  = wkt + NW;
    short* wot  = wvt + NW;

    prep_kernel<<<3648, 256, 0, stream>>>(tgt, qpos, Wq, Wk, Wv, Wo,
                                          aqk, av, wqt, wkt, wvt, wot);

    gemm_qkv<<<dim3(18, 64), 256, 0, stream>>>(aqk, av, wqt, bq, qb,
                                               wkt, bk, kb, wvt, bv, vtb);

    attn_mfma<<<dim3(12, 128), 256, 0, stream>>>(qb, kb, vtb, ploc, Wloc, bloc, aob);

    gemm_o<<<dim3(6, 64), 256, 0, stream>>>(aob, wot, bo, pbuf);

    ln_kernel<<<MM, 256, 0, stream>>>(pbuf, tgt, ln_g, ln_b, (float*)d_out);
}